// Round 5
// baseline (392.418 us; speedup 1.0000x reference)
//
#include <hip/hip_runtime.h>

// Flow1: RealNVP coupling flow. K=32 B=4096 ZS=128 ZH=64 HS=50 NF=2.
// Round 5: single fused kernel (no convert pre-kernel). Per wave: 32 rows
// (2 M-tiles). Per step: block converts the step's 3 weight mats fp32->bf16
// padded [o][72] into LDS (re-stride, k already contiguous in source), then
// H = tanh(Zact@B0+b0) via 16x16x32 bf16 MFMA, MEW/SIG via B1/B2 (k>=50
// zero-padded). h overlays the z-active LDS buffer (z frags are fully in
// regs before h writes; in-wave ds ordering is guaranteed by aliasing).
// LDS 46080 B/block -> 3 blocks/CU (12 waves/CU vs round-4's ~4).
// Layouts (m89/m91-verified): A-frag A[m][k] m=lane&15,k=quad*8+j;
// B-frag B[k][o] o=lane&15; C/D D[m][o] o=lane&15, m=quad*4+reg.

typedef unsigned short ushort_t;
typedef unsigned int   uint_t;
typedef short bf8 __attribute__((ext_vector_type(8)));
typedef float f4  __attribute__((ext_vector_type(4)));

#define KK   32
#define BB   4096
#define ZSD  128
#define ZHD  64
#define HSD  50
#define NROWS (KK*BB)

#define WST  72                 // k-stride (shorts): 144B rows, 16B-aligned,
                                // bank-stride 36%32=4 -> only 2-way (free)
#define MATS (64*WST)           // 4608 shorts per padded matrix
#define MATW (MATS/2)           // 2304 u32 words per matrix

__device__ __forceinline__ ushort_t f2bf(float f){
  union{float f; uint_t i;} v; v.f = f;
  uint_t x = v.i;
  return (ushort_t)((x + 0x7fffu + ((x>>16)&1u)) >> 16);   // RNE
}
__device__ __forceinline__ uint_t pkbf(float lo, float hi){
  return (uint_t)f2bf(lo) | ((uint_t)f2bf(hi) << 16);
}

__device__ __forceinline__ float tanh_fast(float x){
  float ax = fabsf(x);
  float t  = __expf(-2.0f*ax);                       // (0,1]
  float r  = (1.0f - t) * __builtin_amdgcn_rcpf(1.0f + t);
  union{float f; uint_t i;} u, s; u.f = r; s.f = x;
  u.i |= (s.i & 0x80000000u);
  return u.f;
}

__device__ __forceinline__ void sigmoid_log(float x, float& sig, float& lsig){
  float ax  = fabsf(x);
  float e   = __expf(-ax);
  float d   = 1.0f + e;
  float inv = __builtin_amdgcn_rcpf(d);
  float ld  = __logf(d);
  bool pos  = (x >= 0.0f);
  sig  = pos ? inv : e*inv;
  lsig = pos ? -ld : x - ld;
}

__device__ __forceinline__ f4 MFMA(bf8 a, bf8 b, f4 c){
  return __builtin_amdgcn_mfma_f32_16x16x32_bf16(a, b, c, 0, 0, 0);
}

// ---- one coupling step ----------------------------------------------------
__device__ __forceinline__ void do_step(
    int s, float (&pz)[2][16], float (&T)[2][4],
    ushort_t* zAw, ushort_t* wsh,
    const float* __restrict__ W0g, const float* __restrict__ b0g,
    const float* __restrict__ W1g, const float* __restrict__ b1g,
    const float* __restrict__ W2g, const float* __restrict__ b2g,
    int tid, int quad, int l15, int wr)
{
  // ---- stage + convert this step's weights into LDS (block-shared) ----
  __syncthreads();                       // prior step's frag reads done
  {
    uint_t* w32 = (uint_t*)wsh;
    const float* W0s = W0g + s*(HSD*ZHD);        // [50][64], k=z contiguous
    #pragma unroll
    for (int it=0; it<9; ++it){                  // 2304/256
      int p = it*256 + tid;
      int o = p / 36, kc = p - o*36;             // k = 2*kc
      float2 v = make_float2(0.f, 0.f);
      if (o < HSD && kc < 32) v = *(const float2*)(W0s + o*ZHD + 2*kc);
      w32[p] = pkbf(v.x, v.y);
    }
    #pragma unroll
    for (int mi=1; mi<=2; ++mi){
      const float* Ws = (mi==1 ? W1g : W2g) + s*(ZHD*HSD);  // [64][50]
      #pragma unroll
      for (int it=0; it<9; ++it){
        int p = it*256 + tid;
        int o = p / 36, kc = p - o*36;
        float2 v = make_float2(0.f, 0.f);
        if (kc < 25) v = *(const float2*)(Ws + o*HSD + 2*kc);
        w32[mi*MATW + p] = pkbf(v.x, v.y);
      }
    }
  }
  __syncthreads();

  // ---- phase A: H = tanh(Zact @ B0 + b0), h overlays zAw ----
  bf8 zf[2][2];
  #pragma unroll
  for (int m=0;m<2;++m)
    #pragma unroll
    for (int kt=0;kt<2;++kt)
      zf[m][kt] = *(const bf8*)(zAw + (m*16 + l15)*WST + kt*32 + quad*8);

  #pragma unroll
  for (int nt=0;nt<4;++nt){
    int o = nt*16 + l15;
    const ushort_t* wb = wsh + o*WST + quad*8;
    bf8 w0a = *(const bf8*)(wb);
    bf8 w0b = *(const bf8*)(wb + 32);
    float b0v = (o < HSD) ? b0g[s*HSD + o] : 0.f;
    #pragma unroll
    for (int m=0;m<2;++m){
      f4 acc = {0.f,0.f,0.f,0.f};
      acc = MFMA(zf[m][0], w0a, acc);
      acc = MFMA(zf[m][1], w0b, acc);
      #pragma unroll
      for (int i=0;i<4;++i){
        float h = tanh_fast(acc[i] + b0v);
        zAw[(m*16 + quad*4 + i)*WST + o] = f2bf(h);
      }
    }
  }

  // ---- phase B: MEW = H@B1+b1 ; SIG = sigmoid(H@B2+b2) ----
  bf8 hf[2][2];
  #pragma unroll
  for (int m=0;m<2;++m)
    #pragma unroll
    for (int kt=0;kt<2;++kt)
      hf[m][kt] = *(const bf8*)(zAw + (m*16 + l15)*WST + kt*32 + quad*8);

  #pragma unroll
  for (int nt=0;nt<4;++nt){
    int o = nt*16 + l15;
    const ushort_t* w1p = wsh + (1*64 + o)*WST + quad*8;
    const ushort_t* w2p = wsh + (2*64 + o)*WST + quad*8;
    bf8 w1a = *(const bf8*)(w1p);
    bf8 w1b = *(const bf8*)(w1p + 32);
    bf8 w2a = *(const bf8*)(w2p);
    bf8 w2b = *(const bf8*)(w2p + 32);
    float b1v = b1g[s*ZHD + o];
    float b2v = b2g[s*ZHD + o];
    #pragma unroll
    for (int m=0;m<2;++m){
      f4 am = {0.f,0.f,0.f,0.f};
      f4 as = {0.f,0.f,0.f,0.f};
      am = MFMA(hf[m][0], w1a, am);
      am = MFMA(hf[m][1], w1b, am);
      as = MFMA(hf[m][0], w2a, as);
      as = MFMA(hf[m][1], w2b, as);
      #pragma unroll
      for (int i=0;i<4;++i){
        float mew  = am[i] + b1v;
        float spre = as[i] + b2v;
        float sig, lsig;
        sigmoid_log(spre, sig, lsig);
        pz[m][nt*4+i] = fmaf(pz[m][nt*4+i], sig, mew);
        T[m][i] += lsig;
      }
    }
  }

  // new active = just-updated passive (bf16, A-layout over zAw)
  if (wr){
    #pragma unroll
    for (int m=0;m<2;++m)
      #pragma unroll
      for (int nt=0;nt<4;++nt)
        #pragma unroll
        for (int i=0;i<4;++i)
          zAw[(m*16 + quad*4 + i)*WST + nt*16 + l15] = f2bf(pz[m][nt*4+i]);
  }
}

__global__ __launch_bounds__(256, 3) void flow_fused(
    const float* __restrict__ mean, const float* __restrict__ logvar,
    const float* __restrict__ eps,
    const float* __restrict__ W0g, const float* __restrict__ b0g,
    const float* __restrict__ W1g, const float* __restrict__ b1g,
    const float* __restrict__ W2g, const float* __restrict__ b2g,
    float* __restrict__ out)
{
  __shared__ __align__(16) ushort_t wsh[3*MATS];        // 27648 B
  __shared__ __align__(16) ushort_t zA[4][32*WST];      // 18432 B -> 46080 B total

  const int tid  = threadIdx.x;
  const int wave = tid >> 6;
  const int lane = tid & 63;
  const int quad = lane >> 4;
  const int l15  = lane & 15;
  const int rbase = blockIdx.x*128 + wave*32;

  ushort_t* zAw = zA[wave];

  float z1D[2][16], z2D[2][16];     // C/D layout: row=m*16+quad*4+i, col=nt*16+l15
  float T[2][4];                    // 0.5*sum(lv+eps^2) + sum(lsig)

  // ---- init: z = eps*exp(0.5*lv)+mean, loaded directly in D-layout ----
  #pragma unroll
  for (int m=0;m<2;++m){
    #pragma unroll
    for (int i=0;i<4;++i){
      int rrow = rbase + m*16 + quad*4 + i;
      int brow = rrow & (BB-1);
      const float* er = eps    + (size_t)rrow*ZSD;
      const float* mr = mean   + (size_t)brow*ZSD;
      const float* vr = logvar + (size_t)brow*ZSD;
      float acc = 0.f;
      #pragma unroll
      for (int nt=0;nt<4;++nt){
        int c1 = nt*16 + l15;
        int c2 = 64 + c1;
        float e1 = er[c1], v1 = vr[c1], m1 = mr[c1];
        float e2 = er[c2], v2 = vr[c2], m2 = mr[c2];
        z1D[m][nt*4+i] = fmaf(e1, __expf(0.5f*v1), m1);
        z2D[m][nt*4+i] = fmaf(e2, __expf(0.5f*v2), m2);
        acc += (v1 + e1*e1) + (v2 + e2*e2);
      }
      T[m][i] = 0.5f*acc;
    }
  }

  // initial active = z1 -> zA (bf16, A-layout)
  #pragma unroll
  for (int m=0;m<2;++m)
    #pragma unroll
    for (int nt=0;nt<4;++nt)
      #pragma unroll
      for (int i=0;i<4;++i)
        zAw[(m*16 + quad*4 + i)*WST + nt*16 + l15] = f2bf(z1D[m][nt*4+i]);

  // ---- 4 coupling steps ----
  #pragma unroll 1
  for (int it=0; it<2; ++it){
    do_step(2*it+0, z2D, T, zAw, wsh, W0g,b0g,W1g,b1g,W2g,b2g, tid, quad, l15, 1);
    do_step(2*it+1, z1D, T, zAw, wsh, W0g,b0g,W1g,b1g,W2g,b2g, tid, quad, l15, it==0);
  }

  // ---- store z_out (fp32) ----
  #pragma unroll
  for (int m=0;m<2;++m){
    #pragma unroll
    for (int i=0;i<4;++i){
      int rrow = rbase + m*16 + quad*4 + i;
      float* orow = out + (size_t)rrow*ZSD;
      #pragma unroll
      for (int nt=0;nt<4;++nt){
        orow[nt*16 + l15]      = z1D[m][nt*4+i];
        orow[64 + nt*16 + l15] = z2D[m][nt*4+i];
      }
    }
  }

  // ---- logpz: reduce T across the 16 lanes of each quad ----
  #pragma unroll
  for (int m=0;m<2;++m)
    #pragma unroll
    for (int i=0;i<4;++i){
      float v = T[m][i];
      v += __shfl_xor(v, 1, 64);
      v += __shfl_xor(v, 2, 64);
      v += __shfl_xor(v, 4, 64);
      v += __shfl_xor(v, 8, 64);
      T[m][i] = v;
    }
  if (l15 == 0){
    const float NC = -0.5f * 128.0f * 1.8378770664093453f;
    #pragma unroll
    for (int m=0;m<2;++m)
      #pragma unroll
      for (int i=0;i<4;++i){
        int rrow = rbase + m*16 + quad*4 + i;
        out[(size_t)NROWS*ZSD + rrow] = NC - T[m][i];
      }
  }
}

extern "C" void kernel_launch(void* const* d_in, const int* in_sizes, int n_in,
                              void* d_out, int out_size, void* d_ws, size_t ws_size,
                              hipStream_t stream)
{
  const float* mean   = (const float*)d_in[0];
  const float* logvar = (const float*)d_in[1];
  const float* eps    = (const float*)d_in[2];
  const float* W0     = (const float*)d_in[3];
  const float* b0     = (const float*)d_in[4];
  const float* W1     = (const float*)d_in[5];
  const float* b1     = (const float*)d_in[6];
  const float* W2     = (const float*)d_in[7];
  const float* b2     = (const float*)d_in[8];

  flow_fused<<<NROWS/128, 256, 0, stream>>>(
      mean, logvar, eps, W0, b0, W1, b1, W2, b2, (float*)d_out);
}